// Round 1
// baseline (1177.674 us; speedup 1.0000x reference)
//
#include <hip/hip_runtime.h>
#include <hip/hip_bf16.h>

#define CCH   192
#define HIDN  768
#define IMH   128
#define IMW   128
#define BT    131072   // B * H * W tokens
#define TM    64       // tokens per block in fused kernel

typedef short bf8 __attribute__((ext_vector_type(8)));
typedef float f32x4 __attribute__((ext_vector_type(4)));

__device__ __forceinline__ short f2bf(float f) {
  union { float f; unsigned u; } uf; uf.f = f;
  unsigned r = uf.u + 0x7fffu + ((uf.u >> 16) & 1u);
  return (short)(r >> 16);
}
__device__ __forceinline__ float bf2f(short s) {
  union { unsigned u; float f; } uf;
  uf.u = ((unsigned)(unsigned short)s) << 16;
  return uf.f;
}

// ---------------- prep: weight bf16 conversion + folded conv kernel --------
__global__ __launch_bounds__(256) void prep_kernel(
    const float* __restrict__ Wk, const float* __restrict__ Wv,
    const float* __restrict__ Wr, const float* __restrict__ w1,
    const float* __restrict__ w3, const float* __restrict__ w5,
    const float* __restrict__ alpha,
    short* __restrict__ Wkb, short* __restrict__ Wvb, short* __restrict__ Wrb,
    float* __restrict__ weff) {
  int i = blockIdx.x * 256 + threadIdx.x;
  if (i < HIDN * CCH) Wkb[i] = f2bf(Wk[i]);
  if (i < CCH * HIDN) Wvb[i] = f2bf(Wv[i]);
  if (i < CCH * CCH)  Wrb[i] = f2bf(Wr[i]);
  if (i < 25 * CCH) {
    int j = i / CCH, c = i % CCH;
    int di = j / 5, dj = j % 5;
    float v = alpha[3] * w5[c * 25 + j];
    if (di >= 1 && di <= 3 && dj >= 1 && dj <= 3)
      v += alpha[2] * w3[c * 9 + (di - 1) * 3 + (dj - 1)];
    if (di == 2 && dj == 2) v += alpha[1] * w1[c] + alpha[0];
    weff[j * CCH + c] = v;  // layout [tap][channel] for coalesced reads
  }
}

// ---------------- conv: OmniShift 5x5 folded depthwise, channel-last ------
__global__ __launch_bounds__(192) void conv_kernel(
    const float* __restrict__ x, const float* __restrict__ weff,
    short* __restrict__ xx) {
  int g = blockIdx.x;          // global pixel index (b*T + p)
  int c = threadIdx.x;         // channel
  int p = g & (IMH * IMW - 1);
  int h = p >> 7, w = p & (IMW - 1);
  const float* xb = x + (long)(g - p) * CCH;  // image base

  float acc = 0.f;
#pragma unroll
  for (int di = 0; di < 5; ++di) {
    int hh = h + di - 2;
    if (hh < 0 || hh >= IMH) continue;
#pragma unroll
    for (int dj = 0; dj < 5; ++dj) {
      int ww = w + dj - 2;
      if (ww < 0 || ww >= IMW) continue;
      acc += weff[(di * 5 + dj) * CCH + c] * xb[(hh * IMW + ww) * CCH + c];
    }
  }
  xx[(long)g * CCH + c] = f2bf(acc);
}

// ---------------- fused: mix -> GEMM1 -> relu^2 -> LN -> GEMM2/3 -> out ---
__global__ __launch_bounds__(512) void fused_kernel(
    const float* __restrict__ x, const short* __restrict__ xx,
    const float* __restrict__ mixk, const float* __restrict__ mixr,
    const short* __restrict__ Wkb, const short* __restrict__ Wvb,
    const short* __restrict__ Wrb, const float* __restrict__ lng,
    const float* __restrict__ lnb, float* __restrict__ out) {
  extern __shared__ char smem[];
  short* xk_s = (short*)smem;                   // 64 x 200 shorts = 25600 B
  short* xr_s = (short*)(smem + 25600);         // 25600 B
  short* kh_s = (short*)(smem + 51200);         // 64 x 776 shorts = 99328 B
  float* psum = (float*)(smem + 150528);        // [2][64]
  float* psq  = (float*)(smem + 151040);        // [2][64]
  float* mu_s = (float*)(smem + 151552);        // [64]
  float* rs_s = (float*)(smem + 151808);        // [64]

  const int tid  = threadIdx.x;
  const int wave = tid >> 6, lane = tid & 63;
  const int rg = wave & 3, chh = wave >> 2;     // row-group, col-half
  const int m = lane & 15, q = lane >> 4;       // mfma lane decomposition
  const int r0 = rg * 16;
  const int t0 = blockIdx.x * TM;

  // ---- stage xk, xr tiles (bf16, padded stride 200) ----
  for (int it = 0; it < 3; ++it) {
    int chunk = it * 512 + tid;                 // 64 rows * 24 chunks
    int row = chunk / 24, c8 = (chunk % 24) * 8;
    int gidx = (t0 + row) * CCH + c8;
    f32x4 a0 = *(const f32x4*)(x + gidx);
    f32x4 a1 = *(const f32x4*)(x + gidx + 4);
    bf8 xv = *(const bf8*)(xx + gidx);
    f32x4 mk0 = *(const f32x4*)(mixk + c8);
    f32x4 mk1 = *(const f32x4*)(mixk + c8 + 4);
    f32x4 mr0 = *(const f32x4*)(mixr + c8);
    f32x4 mr1 = *(const f32x4*)(mixr + c8 + 4);
    bf8 ok, orv;
#pragma unroll
    for (int j = 0; j < 8; ++j) {
      float xf  = (j < 4) ? a0[j] : a1[j - 4];
      float xxf = bf2f(xv[j]);
      float mk  = (j < 4) ? mk0[j] : mk1[j - 4];
      float mr  = (j < 4) ? mr0[j] : mr1[j - 4];
      ok[j]  = f2bf(xf * mk + xxf * (1.f - mk));
      orv[j] = f2bf(xf * mr + xxf * (1.f - mr));
    }
    *(bf8*)(xk_s + row * 200 + c8) = ok;
    *(bf8*)(xr_s + row * 200 + c8) = orv;
  }
  __syncthreads();

  // ---- GEMM1: k_pre = xk @ Wk^T  [64 x 768], relu^2, write kh_s ----
  bf8 af[6];
#pragma unroll
  for (int kk = 0; kk < 6; ++kk)
    af[kk] = *(const bf8*)(xk_s + (r0 + m) * 200 + kk * 32 + q * 8);

  float rsum[4] = {0.f, 0.f, 0.f, 0.f};
  float rsq[4]  = {0.f, 0.f, 0.f, 0.f};
  for (int ctg = 0; ctg < 6; ++ctg) {           // 24 col-tiles per half, 4/iter
    f32x4 acc[4];
#pragma unroll
    for (int u = 0; u < 4; ++u) acc[u] = (f32x4){0.f, 0.f, 0.f, 0.f};
    int h0base = (chh * 24 + ctg * 4) * 16;
#pragma unroll
    for (int kk = 0; kk < 6; ++kk) {
#pragma unroll
      for (int u = 0; u < 4; ++u) {
        int hrow = h0base + u * 16 + m;
        bf8 bfr = *(const bf8*)(Wkb + hrow * CCH + kk * 32 + q * 8);
        acc[u] = __builtin_amdgcn_mfma_f32_16x16x32_bf16(af[kk], bfr, acc[u], 0, 0, 0);
      }
    }
#pragma unroll
    for (int u = 0; u < 4; ++u) {
      int col = h0base + u * 16 + m;
#pragma unroll
      for (int i = 0; i < 4; ++i) {
        float v = acc[u][i];
        v = fmaxf(v, 0.f);
        v = v * v;
        rsum[i] += v;
        rsq[i]  += v * v;
        kh_s[(r0 + q * 4 + i) * 776 + col] = f2bf(v);
      }
    }
  }

  // ---- per-row LN stats: butterfly over the 16 lanes of each quad ----
#pragma unroll
  for (int d = 1; d < 16; d <<= 1) {
#pragma unroll
    for (int i = 0; i < 4; ++i) {
      rsum[i] += __shfl_xor(rsum[i], d, 64);
      rsq[i]  += __shfl_xor(rsq[i], d, 64);
    }
  }
  if (m == 0) {
#pragma unroll
    for (int i = 0; i < 4; ++i) {
      psum[chh * TM + r0 + q * 4 + i] = rsum[i];
      psq[chh * TM + r0 + q * 4 + i]  = rsq[i];
    }
  }
  __syncthreads();
  if (tid < TM) {
    float s  = psum[tid] + psum[TM + tid];
    float sq = psq[tid] + psq[TM + tid];
    float mu = s * (1.f / (float)HIDN);
    float var = sq * (1.f / (float)HIDN) - mu * mu;
    mu_s[tid] = mu;
    rs_s[tid] = rsqrtf(var + 1e-5f);
  }
  __syncthreads();

  // ---- normalize kh in LDS: (v - mu) * rstd * g + b ----
  for (int it = 0; it < 12; ++it) {
    int chunk = it * 512 + tid;                 // 64 rows * 96 chunks
    int row = chunk / 96, c8 = (chunk % 96) * 8;
    float mu = mu_s[row], rs = rs_s[row];
    bf8 v = *(bf8*)(kh_s + row * 776 + c8);
    f32x4 g0 = *(const f32x4*)(lng + c8);
    f32x4 g1 = *(const f32x4*)(lng + c8 + 4);
    f32x4 b0 = *(const f32x4*)(lnb + c8);
    f32x4 b1 = *(const f32x4*)(lnb + c8 + 4);
    bf8 o;
#pragma unroll
    for (int j = 0; j < 8; ++j) {
      float g = (j < 4) ? g0[j] : g1[j - 4];
      float b = (j < 4) ? b0[j] : b1[j - 4];
      o[j] = f2bf((bf2f(v[j]) - mu) * rs * g + b);
    }
    *(bf8*)(kh_s + row * 776 + c8) = o;
  }
  __syncthreads();

  // ---- GEMM3: r_pre = xr @ Wr^T  (6 col-tiles of 16 per wave) ----
  bf8 ar[6];
#pragma unroll
  for (int kk = 0; kk < 6; ++kk)
    ar[kk] = *(const bf8*)(xr_s + (r0 + m) * 200 + kk * 32 + q * 8);
  f32x4 racc[6];
#pragma unroll
  for (int u = 0; u < 6; ++u) racc[u] = (f32x4){0.f, 0.f, 0.f, 0.f};
#pragma unroll
  for (int kk = 0; kk < 6; ++kk) {
#pragma unroll
    for (int u = 0; u < 6; ++u) {
      int drow = (chh * 6 + u) * 16 + m;
      bf8 bfr = *(const bf8*)(Wrb + drow * CCH + kk * 32 + q * 8);
      racc[u] = __builtin_amdgcn_mfma_f32_16x16x32_bf16(ar[kk], bfr, racc[u], 0, 0, 0);
    }
  }

  // ---- GEMM2: kv = khat @ Wv^T  (6 col-tiles of 16 per wave) ----
  f32x4 vacc[6];
#pragma unroll
  for (int u = 0; u < 6; ++u) vacc[u] = (f32x4){0.f, 0.f, 0.f, 0.f};
#pragma unroll 4
  for (int kk = 0; kk < 24; ++kk) {
    bf8 a = *(const bf8*)(kh_s + (r0 + m) * 776 + kk * 32 + q * 8);
#pragma unroll
    for (int u = 0; u < 6; ++u) {
      int crow = (chh * 6 + u) * 16 + m;
      bf8 bfr = *(const bf8*)(Wvb + crow * HIDN + kk * 32 + q * 8);
      vacc[u] = __builtin_amdgcn_mfma_f32_16x16x32_bf16(a, bfr, vacc[u], 0, 0, 0);
    }
  }

  // ---- epilogue: out = sigmoid(r_pre) * kv ----
#pragma unroll
  for (int u = 0; u < 6; ++u) {
    int col = (chh * 6 + u) * 16 + m;
#pragma unroll
    for (int i = 0; i < 4; ++i) {
      float rp = racc[u][i];
      float sig = 1.f / (1.f + __expf(-rp));
      float o = sig * vacc[u][i];
      out[(t0 + r0 + q * 4 + i) * CCH + col] = o;
    }
  }
}

// ---------------- launch ---------------------------------------------------
extern "C" void kernel_launch(void* const* d_in, const int* in_sizes, int n_in,
                              void* d_out, int out_size, void* d_ws, size_t ws_size,
                              hipStream_t stream) {
  const float* x     = (const float*)d_in[0];
  const float* w1    = (const float*)d_in[1];
  const float* w3    = (const float*)d_in[2];
  const float* w5    = (const float*)d_in[3];
  const float* alpha = (const float*)d_in[4];
  const float* mixk  = (const float*)d_in[5];
  const float* mixr  = (const float*)d_in[6];
  const float* Wk    = (const float*)d_in[7];
  const float* lng   = (const float*)d_in[8];
  const float* lnb   = (const float*)d_in[9];
  const float* Wr    = (const float*)d_in[10];
  const float* Wv    = (const float*)d_in[11];
  float* out = (float*)d_out;

  char* ws = (char*)d_ws;
  short* Wkb  = (short*)(ws);              // 768*192*2 = 294912
  short* Wvb  = (short*)(ws + 294912);     // 294912
  short* Wrb  = (short*)(ws + 589824);     // 73728
  float* weff = (float*)(ws + 663552);     // 25*192*4 = 19200
  short* xxb  = (short*)(ws + 682752);     // 131072*192*2 = 50331648

  prep_kernel<<<576, 256, 0, stream>>>(Wk, Wv, Wr, w1, w3, w5, alpha,
                                       Wkb, Wvb, Wrb, weff);
  conv_kernel<<<BT, 192, 0, stream>>>(x, weff, xxb);
  fused_kernel<<<BT / TM, 512, 152064, stream>>>(x, xxb, mixk, mixr,
                                                 Wkb, Wvb, Wrb, lng, lnb, out);
}

// Round 2
// 767.780 us; speedup vs baseline: 1.5339x; 1.5339x over previous
//
#include <hip/hip_runtime.h>
#include <hip/hip_bf16.h>

#define CCH   192
#define HIDN  768
#define IMH   128
#define IMW   128
#define BT    131072   // B * H * W tokens
#define TM    32       // tokens per block in fused kernel

typedef short bf8 __attribute__((ext_vector_type(8)));
typedef short bf4 __attribute__((ext_vector_type(4)));
typedef float f32x4 __attribute__((ext_vector_type(4)));

__device__ __forceinline__ short f2bf(float f) {
  union { float f; unsigned u; } uf; uf.f = f;
  unsigned r = uf.u + 0x7fffu + ((uf.u >> 16) & 1u);
  return (short)(r >> 16);
}
__device__ __forceinline__ float bf2f(short s) {
  union { unsigned u; float f; } uf;
  uf.u = ((unsigned)(unsigned short)s) << 16;
  return uf.f;
}

// ---------------- prep: weight bf16 conversion + folded conv kernel --------
__global__ __launch_bounds__(256) void prep_kernel(
    const float* __restrict__ Wk, const float* __restrict__ Wv,
    const float* __restrict__ Wr, const float* __restrict__ w1,
    const float* __restrict__ w3, const float* __restrict__ w5,
    const float* __restrict__ alpha,
    short* __restrict__ Wkb, short* __restrict__ Wvb, short* __restrict__ Wrb,
    float* __restrict__ weff) {
  int i = blockIdx.x * 256 + threadIdx.x;
  if (i < HIDN * CCH) Wkb[i] = f2bf(Wk[i]);
  if (i < CCH * HIDN) Wvb[i] = f2bf(Wv[i]);
  if (i < CCH * CCH)  Wrb[i] = f2bf(Wr[i]);
  if (i < 25 * CCH) {
    int j = i / CCH, c = i % CCH;
    int di = j / 5, dj = j % 5;
    float v = alpha[3] * w5[c * 25 + j];
    if (di >= 1 && di <= 3 && dj >= 1 && dj <= 3)
      v += alpha[2] * w3[c * 9 + (di - 1) * 3 + (dj - 1)];
    if (di == 2 && dj == 2) v += alpha[1] * w1[c] + alpha[0];
    weff[j * CCH + c] = v;  // layout [tap][channel] for coalesced reads
  }
}

// ---- fused: conv+mix -> GEMM1 -> relu^2 -> LN -> GEMM3/GEMM2 -> out ------
__global__ __launch_bounds__(512, 4) void fused_kernel(
    const float* __restrict__ x, const float* __restrict__ weff,
    const float* __restrict__ mixk, const float* __restrict__ mixr,
    const short* __restrict__ Wkb, const short* __restrict__ Wvb,
    const short* __restrict__ Wrb, const float* __restrict__ lng,
    const float* __restrict__ lnb, float* __restrict__ out) {
  extern __shared__ char smem[];
  short* xk_s = (short*)smem;                   // 32 x 200 shorts = 12800 B
  short* xr_s = (short*)(smem + 12800);         // 12800 B
  short* kh_s = (short*)(smem + 25600);         // 32 x 776 shorts = 49664 B
  float* psum = (float*)(smem + 75264);         // [8][32] = 1024 B
  float* psq  = (float*)(smem + 76288);         // [8][32] = 1024 B
  float* mu_s = (float*)(smem + 77312);         // [32]
  float* rs_s = (float*)(smem + 77440);         // [32]

  const int tid  = threadIdx.x;
  const int wave = tid >> 6, lane = tid & 63;
  const int oct  = wave;                        // GEMM1: col-octant (96 cols)
  const int rg   = wave & 1, chh = wave >> 1;   // GEMM2/3: row-group, col-quarter
  const int m = lane & 15, q = lane >> 4;       // mfma lane decomposition
  const int r0 = rg * 16;
  const int t0 = blockIdx.x * TM;

  // ---- conv (OmniShift folded 5x5) + token mix, staged to LDS bf16 ----
  const int b  = t0 >> 14;                      // image index
  const int p  = t0 & 16383;
  const int h  = p >> 7;                        // row (uniform for block)
  const int w0 = p & 127;                       // first col (0/32/64/96)
  const float* xim = x + (long)b * (16384L * CCH);

  for (int it = 0; it < 3; ++it) {
    int idx = it * 512 + tid;                   // 32 tok * 48 c4-groups
    int tok = idx / 48, c = (idx % 48) * 4;
    int w = w0 + tok;
    f32x4 acc = {0.f, 0.f, 0.f, 0.f};
    f32x4 xc  = {0.f, 0.f, 0.f, 0.f};
#pragma unroll
    for (int di = 0; di < 5; ++di) {
      int hh = h + di - 2;
      if (hh < 0 || hh >= IMH) continue;
      const float* xrow = xim + ((long)hh * IMW) * CCH + c;
#pragma unroll
      for (int dj = 0; dj < 5; ++dj) {
        int ww = w + dj - 2;
        f32x4 xv = {0.f, 0.f, 0.f, 0.f};
        if (ww >= 0 && ww < IMW) xv = *(const f32x4*)(xrow + (long)ww * CCH);
        f32x4 wv = *(const f32x4*)(weff + (di * 5 + dj) * CCH + c);
        acc += xv * wv;
        if (di == 2 && dj == 2) xc = xv;
      }
    }
    f32x4 mk = *(const f32x4*)(mixk + c);
    f32x4 mr = *(const f32x4*)(mixr + c);
    bf4 ok, orv;
#pragma unroll
    for (int j = 0; j < 4; ++j) {
      ok[j]  = f2bf(xc[j] * mk[j] + acc[j] * (1.f - mk[j]));
      orv[j] = f2bf(xc[j] * mr[j] + acc[j] * (1.f - mr[j]));
    }
    *(bf4*)(xk_s + tok * 200 + c) = ok;
    *(bf4*)(xr_s + tok * 200 + c) = orv;
  }
  __syncthreads();

  // ---- GEMM1: k_pre = xk @ Wk^T [32 x 768]; wave owns 96 cols, 32 rows ----
  f32x4 acc0[6], acc1[6];
#pragma unroll
  for (int u = 0; u < 6; ++u) {
    acc0[u] = (f32x4){0.f, 0.f, 0.f, 0.f};
    acc1[u] = (f32x4){0.f, 0.f, 0.f, 0.f};
  }
  const short* BkW = Wkb + (oct * 96) * CCH;
#pragma unroll
  for (int kk = 0; kk < 6; ++kk) {
    bf8 a0 = *(const bf8*)(xk_s + m * 200 + kk * 32 + q * 8);
    bf8 a1 = *(const bf8*)(xk_s + (16 + m) * 200 + kk * 32 + q * 8);
#pragma unroll
    for (int u = 0; u < 6; ++u) {
      bf8 bfr = *(const bf8*)(BkW + (u * 16 + m) * CCH + kk * 32 + q * 8);
      acc0[u] = __builtin_amdgcn_mfma_f32_16x16x32_bf16(a0, bfr, acc0[u], 0, 0, 0);
      acc1[u] = __builtin_amdgcn_mfma_f32_16x16x32_bf16(a1, bfr, acc1[u], 0, 0, 0);
    }
  }

  // ---- relu^2 in registers + LN partial stats ----
  float rsum0[4] = {0,0,0,0}, rsq0[4] = {0,0,0,0};
  float rsum1[4] = {0,0,0,0}, rsq1[4] = {0,0,0,0};
#pragma unroll
  for (int u = 0; u < 6; ++u) {
#pragma unroll
    for (int i = 0; i < 4; ++i) {
      float v0 = fmaxf(acc0[u][i], 0.f); v0 *= v0;
      float v1 = fmaxf(acc1[u][i], 0.f); v1 *= v1;
      acc0[u][i] = v0; acc1[u][i] = v1;
      rsum0[i] += v0; rsq0[i] += v0 * v0;
      rsum1[i] += v1; rsq1[i] += v1 * v1;
    }
  }
#pragma unroll
  for (int d = 1; d < 16; d <<= 1) {
#pragma unroll
    for (int i = 0; i < 4; ++i) {
      rsum0[i] += __shfl_xor(rsum0[i], d, 64);
      rsq0[i]  += __shfl_xor(rsq0[i], d, 64);
      rsum1[i] += __shfl_xor(rsum1[i], d, 64);
      rsq1[i]  += __shfl_xor(rsq1[i], d, 64);
    }
  }
  if (m == 0) {
#pragma unroll
    for (int i = 0; i < 4; ++i) {
      psum[oct * 32 + q * 4 + i]      = rsum0[i];
      psq[oct * 32 + q * 4 + i]       = rsq0[i];
      psum[oct * 32 + 16 + q * 4 + i] = rsum1[i];
      psq[oct * 32 + 16 + q * 4 + i]  = rsq1[i];
    }
  }

  // ---- GEMM3: r_pre = xr @ Wr^T (before stats barrier; fills the stall) ----
  f32x4 racc[3];
#pragma unroll
  for (int u = 0; u < 3; ++u) racc[u] = (f32x4){0.f, 0.f, 0.f, 0.f};
  const short* BrW = Wrb + (chh * 48) * CCH;
#pragma unroll
  for (int kk = 0; kk < 6; ++kk) {
    bf8 ar = *(const bf8*)(xr_s + (r0 + m) * 200 + kk * 32 + q * 8);
#pragma unroll
    for (int u = 0; u < 3; ++u) {
      bf8 bfr = *(const bf8*)(BrW + (u * 16 + m) * CCH + kk * 32 + q * 8);
      racc[u] = __builtin_amdgcn_mfma_f32_16x16x32_bf16(ar, bfr, racc[u], 0, 0, 0);
    }
  }
  __syncthreads();

  // ---- finalize LN stats ----
  if (tid < 32) {
    float s = 0.f, sq = 0.f;
#pragma unroll
    for (int o = 0; o < 8; ++o) { s += psum[o * 32 + tid]; sq += psq[o * 32 + tid]; }
    float mu = s * (1.f / (float)HIDN);
    float var = sq * (1.f / (float)HIDN) - mu * mu;
    mu_s[tid] = mu;
    rs_s[tid] = rsqrtf(var + 1e-5f);
  }
  __syncthreads();

  // ---- normalize in registers, single LDS write of khat (bf16) ----
  float mu0[4], rs0v[4], mu1[4], rs1v[4];
#pragma unroll
  for (int i = 0; i < 4; ++i) {
    mu0[i]  = mu_s[q * 4 + i];      rs0v[i] = rs_s[q * 4 + i];
    mu1[i]  = mu_s[16 + q * 4 + i]; rs1v[i] = rs_s[16 + q * 4 + i];
  }
#pragma unroll
  for (int u = 0; u < 6; ++u) {
    int col = oct * 96 + u * 16 + m;
    float g = lng[col], bb = lnb[col];
#pragma unroll
    for (int i = 0; i < 4; ++i) {
      kh_s[(q * 4 + i) * 776 + col]      = f2bf((acc0[u][i] - mu0[i]) * rs0v[i] * g + bb);
      kh_s[(16 + q * 4 + i) * 776 + col] = f2bf((acc1[u][i] - mu1[i]) * rs1v[i] * g + bb);
    }
  }
  __syncthreads();

  // ---- GEMM2: kv = khat @ Wv^T (wave: col-quarter x row-group) ----
  f32x4 vacc[3];
#pragma unroll
  for (int u = 0; u < 3; ++u) vacc[u] = (f32x4){0.f, 0.f, 0.f, 0.f};
  const short* BvW = Wvb + (chh * 48) * HIDN;
#pragma unroll
  for (int kk = 0; kk < 24; ++kk) {
    bf8 a = *(const bf8*)(kh_s + (r0 + m) * 776 + kk * 32 + q * 8);
#pragma unroll
    for (int u = 0; u < 3; ++u) {
      bf8 bfr = *(const bf8*)(BvW + (u * 16 + m) * HIDN + kk * 32 + q * 8);
      vacc[u] = __builtin_amdgcn_mfma_f32_16x16x32_bf16(a, bfr, vacc[u], 0, 0, 0);
    }
  }

  // ---- epilogue: out = sigmoid(r_pre) * kv ----
#pragma unroll
  for (int u = 0; u < 3; ++u) {
    int col = chh * 48 + u * 16 + m;
#pragma unroll
    for (int i = 0; i < 4; ++i) {
      float sig = 1.f / (1.f + __expf(-racc[u][i]));
      out[(long)(t0 + r0 + q * 4 + i) * CCH + col] = sig * vacc[u][i];
    }
  }
}

// ---------------- launch ---------------------------------------------------
extern "C" void kernel_launch(void* const* d_in, const int* in_sizes, int n_in,
                              void* d_out, int out_size, void* d_ws, size_t ws_size,
                              hipStream_t stream) {
  const float* x     = (const float*)d_in[0];
  const float* w1    = (const float*)d_in[1];
  const float* w3    = (const float*)d_in[2];
  const float* w5    = (const float*)d_in[3];
  const float* alpha = (const float*)d_in[4];
  const float* mixk  = (const float*)d_in[5];
  const float* mixr  = (const float*)d_in[6];
  const float* Wk    = (const float*)d_in[7];
  const float* lng   = (const float*)d_in[8];
  const float* lnb   = (const float*)d_in[9];
  const float* Wr    = (const float*)d_in[10];
  const float* Wv    = (const float*)d_in[11];
  float* out = (float*)d_out;

  char* ws = (char*)d_ws;
  short* Wkb  = (short*)(ws);              // 768*192*2 = 294912
  short* Wvb  = (short*)(ws + 294912);     // 294912
  short* Wrb  = (short*)(ws + 589824);     // 73728
  float* weff = (float*)(ws + 663552);     // 25*192*4 = 19200

  prep_kernel<<<576, 256, 0, stream>>>(Wk, Wv, Wr, w1, w3, w5, alpha,
                                       Wkb, Wvb, Wrb, weff);
  fused_kernel<<<BT / TM, 512, 77568, stream>>>(x, weff, mixk, mixr,
                                                Wkb, Wvb, Wrb, lng, lnb, out);
}

// Round 3
// 484.552 us; speedup vs baseline: 2.4304x; 1.5845x over previous
//
#include <hip/hip_runtime.h>
#include <hip/hip_bf16.h>

#define CCH   192
#define HIDN  768
#define IMH   128
#define IMW   128
#define BT    131072   // B * H * W tokens
#define TM    32       // tokens per block in fused kernel

typedef short bf8 __attribute__((ext_vector_type(8)));
typedef short bf4 __attribute__((ext_vector_type(4)));
typedef float f32x4 __attribute__((ext_vector_type(4)));

__device__ __forceinline__ short f2bf(float f) {
  union { float f; unsigned u; } uf; uf.f = f;
  unsigned r = uf.u + 0x7fffu + ((uf.u >> 16) & 1u);
  return (short)(r >> 16);
}

// ---------------- prep: weights -> bf16 MFMA-fragment order + folded conv --
// Fragment order: frag(tile, kk, lane) at ((tile*NK + kk)*64 + lane)*8 shorts,
// holding W[tile*16 + (lane&15)][kk*32 + (lane>>4)*8 .. +8]. A wave's B-load
// is then lane-contiguous (1024 B coalesced) instead of a 16-line gather.
__global__ __launch_bounds__(256) void prep_kernel(
    const float* __restrict__ Wk, const float* __restrict__ Wv,
    const float* __restrict__ Wr, const float* __restrict__ w1,
    const float* __restrict__ w3, const float* __restrict__ w5,
    const float* __restrict__ alpha,
    short* __restrict__ Wkf, short* __restrict__ Wvf, short* __restrict__ Wrf,
    float* __restrict__ weff) {
  int i = blockIdx.x * 256 + threadIdx.x;   // grid covers 18432
  {  // Wk: 48 tiles x 6 kk x 64 lanes = 18432 frags
    int tile = i / 384, rem = i % 384;
    int kk = rem / 64, lane = rem % 64;
    int m = lane & 15, q = lane >> 4;
    const float* src = Wk + (tile * 16 + m) * CCH + kk * 32 + q * 8;
    bf8 o;
#pragma unroll
    for (int j = 0; j < 8; ++j) o[j] = f2bf(src[j]);
    *(bf8*)(Wkf + (long)i * 8) = o;
  }
  {  // Wv: 12 tiles x 24 kk x 64 lanes = 18432 frags
    int tile = i / 1536, rem = i % 1536;
    int kk = rem / 64, lane = rem % 64;
    int m = lane & 15, q = lane >> 4;
    const float* src = Wv + (tile * 16 + m) * HIDN + kk * 32 + q * 8;
    bf8 o;
#pragma unroll
    for (int j = 0; j < 8; ++j) o[j] = f2bf(src[j]);
    *(bf8*)(Wvf + (long)i * 8) = o;
  }
  if (i < 4608) {  // Wr: 12 tiles x 6 kk x 64 lanes
    int tile = i / 384, rem = i % 384;
    int kk = rem / 64, lane = rem % 64;
    int m = lane & 15, q = lane >> 4;
    const float* src = Wr + (tile * 16 + m) * CCH + kk * 32 + q * 8;
    bf8 o;
#pragma unroll
    for (int j = 0; j < 8; ++j) o[j] = f2bf(src[j]);
    *(bf8*)(Wrf + (long)i * 8) = o;
  }
  if (i < 25 * CCH) {
    int j = i / CCH, c = i % CCH;
    int di = j / 5, dj = j % 5;
    float v = alpha[3] * w5[c * 25 + j];
    if (di >= 1 && di <= 3 && dj >= 1 && dj <= 3)
      v += alpha[2] * w3[c * 9 + (di - 1) * 3 + (dj - 1)];
    if (di == 2 && dj == 2) v += alpha[1] * w1[c] + alpha[0];
    weff[j * CCH + c] = v;  // layout [tap][channel] for coalesced reads
  }
}

// ---- fused: conv+mix -> GEMM1 -> relu^2 -> LN -> GEMM3/GEMM2 -> out ------
__global__ __launch_bounds__(512, 4) void fused_kernel(
    const float* __restrict__ x, const float* __restrict__ weff,
    const float* __restrict__ mixk, const float* __restrict__ mixr,
    const short* __restrict__ Wkf, const short* __restrict__ Wvf,
    const short* __restrict__ Wrf, const float* __restrict__ lng,
    const float* __restrict__ lnb, float* __restrict__ out) {
  extern __shared__ char smem[];
  short* xk_s = (short*)smem;                   // 32 x 200 shorts = 12800 B
  short* xr_s = (short*)(smem + 12800);         // 12800 B
  short* kh_s = (short*)(smem + 25600);         // 32 x 776 shorts = 49664 B
  float* psum = (float*)(smem + 75264);         // [8][32] = 1024 B
  float* psq  = (float*)(smem + 76288);         // [8][32] = 1024 B
  float* mu_s = (float*)(smem + 77312);         // [32]
  float* rs_s = (float*)(smem + 77440);         // [32]

  const int tid  = threadIdx.x;
  const int wave = tid >> 6, lane = tid & 63;
  const int oct  = wave;                        // GEMM1: col-octant (96 cols)
  const int rg   = wave & 1, chh = wave >> 1;   // GEMM2/3: row-group, col-quarter
  const int m = lane & 15, q = lane >> 4;       // mfma lane decomposition
  const int r0 = rg * 16;
  const int t0 = blockIdx.x * TM;

  // ---- conv (OmniShift folded 5x5) + token mix, staged to LDS bf16 ----
  const int b  = t0 >> 14;                      // image index
  const int p  = t0 & 16383;
  const int h  = p >> 7;                        // row (uniform for block)
  const int w0 = p & 127;                       // first col (0/32/64/96)
  const float* xim = x + (long)b * (16384L * CCH);

  for (int it = 0; it < 3; ++it) {
    int idx = it * 512 + tid;                   // 32 tok * 48 c4-groups
    int tok = idx / 48, c = (idx % 48) * 4;
    int w = w0 + tok;
    f32x4 acc = {0.f, 0.f, 0.f, 0.f};
    f32x4 xc  = {0.f, 0.f, 0.f, 0.f};
#pragma unroll
    for (int di = 0; di < 5; ++di) {
      int hh = h + di - 2;
      if (hh < 0 || hh >= IMH) continue;
      const float* xrow = xim + ((long)hh * IMW) * CCH + c;
#pragma unroll
      for (int dj = 0; dj < 5; ++dj) {
        int ww = w + dj - 2;
        f32x4 xv = {0.f, 0.f, 0.f, 0.f};
        if (ww >= 0 && ww < IMW) xv = *(const f32x4*)(xrow + (long)ww * CCH);
        f32x4 wv = *(const f32x4*)(weff + (di * 5 + dj) * CCH + c);
        acc += xv * wv;
        if (di == 2 && dj == 2) xc = xv;
      }
    }
    f32x4 mk = *(const f32x4*)(mixk + c);
    f32x4 mr = *(const f32x4*)(mixr + c);
    bf4 ok, orv;
#pragma unroll
    for (int j = 0; j < 4; ++j) {
      ok[j]  = f2bf(xc[j] * mk[j] + acc[j] * (1.f - mk[j]));
      orv[j] = f2bf(xc[j] * mr[j] + acc[j] * (1.f - mr[j]));
    }
    *(bf4*)(xk_s + tok * 200 + c) = ok;
    *(bf4*)(xr_s + tok * 200 + c) = orv;
  }
  __syncthreads();

  // ---- GEMM1: k_pre = xk @ Wk^T [32 x 768]; wave owns 96 cols, 32 rows ----
  f32x4 acc0[6], acc1[6];
#pragma unroll
  for (int u = 0; u < 6; ++u) {
    acc0[u] = (f32x4){0.f, 0.f, 0.f, 0.f};
    acc1[u] = (f32x4){0.f, 0.f, 0.f, 0.f};
  }
  const short* BkW = Wkf + (long)(oct * 6) * (6 * 64 * 8) + lane * 8;
#pragma unroll
  for (int kk = 0; kk < 6; ++kk) {
    bf8 a0 = *(const bf8*)(xk_s + m * 200 + kk * 32 + q * 8);
    bf8 a1 = *(const bf8*)(xk_s + (16 + m) * 200 + kk * 32 + q * 8);
#pragma unroll
    for (int u = 0; u < 6; ++u) {
      bf8 bfr = *(const bf8*)(BkW + (u * 6 + kk) * 512);
      acc0[u] = __builtin_amdgcn_mfma_f32_16x16x32_bf16(a0, bfr, acc0[u], 0, 0, 0);
      acc1[u] = __builtin_amdgcn_mfma_f32_16x16x32_bf16(a1, bfr, acc1[u], 0, 0, 0);
    }
  }

  // ---- relu^2 in registers + LN partial stats ----
  float rsum0[4] = {0,0,0,0}, rsq0[4] = {0,0,0,0};
  float rsum1[4] = {0,0,0,0}, rsq1[4] = {0,0,0,0};
#pragma unroll
  for (int u = 0; u < 6; ++u) {
#pragma unroll
    for (int i = 0; i < 4; ++i) {
      float v0 = fmaxf(acc0[u][i], 0.f); v0 *= v0;
      float v1 = fmaxf(acc1[u][i], 0.f); v1 *= v1;
      acc0[u][i] = v0; acc1[u][i] = v1;
      rsum0[i] += v0; rsq0[i] += v0 * v0;
      rsum1[i] += v1; rsq1[i] += v1 * v1;
    }
  }
#pragma unroll
  for (int d = 1; d < 16; d <<= 1) {
#pragma unroll
    for (int i = 0; i < 4; ++i) {
      rsum0[i] += __shfl_xor(rsum0[i], d, 64);
      rsq0[i]  += __shfl_xor(rsq0[i], d, 64);
      rsum1[i] += __shfl_xor(rsum1[i], d, 64);
      rsq1[i]  += __shfl_xor(rsq1[i], d, 64);
    }
  }
  if (m == 0) {
#pragma unroll
    for (int i = 0; i < 4; ++i) {
      psum[oct * 32 + q * 4 + i]      = rsum0[i];
      psq[oct * 32 + q * 4 + i]       = rsq0[i];
      psum[oct * 32 + 16 + q * 4 + i] = rsum1[i];
      psq[oct * 32 + 16 + q * 4 + i]  = rsq1[i];
    }
  }

  // ---- GEMM3: r_pre = xr @ Wr^T (before stats barrier; fills the stall) ----
  f32x4 racc[3];
#pragma unroll
  for (int u = 0; u < 3; ++u) racc[u] = (f32x4){0.f, 0.f, 0.f, 0.f};
  const short* BrW = Wrf + (long)(chh * 3) * (6 * 64 * 8) + lane * 8;
#pragma unroll
  for (int kk = 0; kk < 6; ++kk) {
    bf8 ar = *(const bf8*)(xr_s + (r0 + m) * 200 + kk * 32 + q * 8);
#pragma unroll
    for (int u = 0; u < 3; ++u) {
      bf8 bfr = *(const bf8*)(BrW + (u * 6 + kk) * 512);
      racc[u] = __builtin_amdgcn_mfma_f32_16x16x32_bf16(ar, bfr, racc[u], 0, 0, 0);
    }
  }
  __syncthreads();

  // ---- finalize LN stats ----
  if (tid < 32) {
    float s = 0.f, sq = 0.f;
#pragma unroll
    for (int o = 0; o < 8; ++o) { s += psum[o * 32 + tid]; sq += psq[o * 32 + tid]; }
    float mu = s * (1.f / (float)HIDN);
    float var = sq * (1.f / (float)HIDN) - mu * mu;
    mu_s[tid] = mu;
    rs_s[tid] = rsqrtf(var + 1e-5f);
  }
  __syncthreads();

  // ---- normalize in registers, single LDS write of khat (bf16) ----
  float mu0[4], rs0v[4], mu1[4], rs1v[4];
#pragma unroll
  for (int i = 0; i < 4; ++i) {
    mu0[i]  = mu_s[q * 4 + i];      rs0v[i] = rs_s[q * 4 + i];
    mu1[i]  = mu_s[16 + q * 4 + i]; rs1v[i] = rs_s[16 + q * 4 + i];
  }
#pragma unroll
  for (int u = 0; u < 6; ++u) {
    int col = oct * 96 + u * 16 + m;
    float g = lng[col], bb = lnb[col];
#pragma unroll
    for (int i = 0; i < 4; ++i) {
      kh_s[(q * 4 + i) * 776 + col]      = f2bf((acc0[u][i] - mu0[i]) * rs0v[i] * g + bb);
      kh_s[(16 + q * 4 + i) * 776 + col] = f2bf((acc1[u][i] - mu1[i]) * rs1v[i] * g + bb);
    }
  }
  __syncthreads();

  // ---- GEMM2: kv = khat @ Wv^T (wave: col-quarter x row-group) ----
  f32x4 vacc[3];
#pragma unroll
  for (int u = 0; u < 3; ++u) vacc[u] = (f32x4){0.f, 0.f, 0.f, 0.f};
  const short* BvW = Wvf + (long)(chh * 3) * (24 * 64 * 8) + lane * 8;
#pragma unroll
  for (int kk = 0; kk < 24; ++kk) {
    bf8 a = *(const bf8*)(kh_s + (r0 + m) * 776 + kk * 32 + q * 8);
#pragma unroll
    for (int u = 0; u < 3; ++u) {
      bf8 bfr = *(const bf8*)(BvW + (u * 24 + kk) * 512);
      vacc[u] = __builtin_amdgcn_mfma_f32_16x16x32_bf16(a, bfr, vacc[u], 0, 0, 0);
    }
  }

  // ---- epilogue: out = sigmoid(r_pre) * kv ----
#pragma unroll
  for (int u = 0; u < 3; ++u) {
    int col = chh * 48 + u * 16 + m;
#pragma unroll
    for (int i = 0; i < 4; ++i) {
      float sig = 1.f / (1.f + __expf(-racc[u][i]));
      out[(long)(t0 + r0 + q * 4 + i) * CCH + col] = sig * vacc[u][i];
    }
  }
}

// ---------------- launch ---------------------------------------------------
extern "C" void kernel_launch(void* const* d_in, const int* in_sizes, int n_in,
                              void* d_out, int out_size, void* d_ws, size_t ws_size,
                              hipStream_t stream) {
  const float* x     = (const float*)d_in[0];
  const float* w1    = (const float*)d_in[1];
  const float* w3    = (const float*)d_in[2];
  const float* w5    = (const float*)d_in[3];
  const float* alpha = (const float*)d_in[4];
  const float* mixk  = (const float*)d_in[5];
  const float* mixr  = (const float*)d_in[6];
  const float* Wk    = (const float*)d_in[7];
  const float* lng   = (const float*)d_in[8];
  const float* lnb   = (const float*)d_in[9];
  const float* Wr    = (const float*)d_in[10];
  const float* Wv    = (const float*)d_in[11];
  float* out = (float*)d_out;

  char* ws = (char*)d_ws;
  short* Wkf  = (short*)(ws);              // 18432 frags * 16 B = 294912
  short* Wvf  = (short*)(ws + 294912);     // 294912
  short* Wrf  = (short*)(ws + 589824);     // 4608 * 16 = 73728
  float* weff = (float*)(ws + 663552);     // 25*192*4 = 19200

  prep_kernel<<<72, 256, 0, stream>>>(Wk, Wv, Wr, w1, w3, w5, alpha,
                                      Wkf, Wvf, Wrf, weff);
  fused_kernel<<<BT / TM, 512, 77568, stream>>>(x, weff, mixk, mixr,
                                                Wkf, Wvf, Wrf, lng, lnb, out);
}